// Round 10
// baseline (391.093 us; speedup 1.0000x reference)
//
#include <hip/hip_runtime.h>
#include <hip/hip_bf16.h>

// ---------------------------------------------------------------------------
// MultiHeadAttention: B=4, T=1024, E=768, D=768, H=8, per-head full-width proj
// 128x128-tile 4-wave bf16 MFMA GEMM + T2 LDS XOR swizzle (0 conflicts) + T1.
// Algebraic fusion: Wvo[h]=wv[h]*wo[h] precomputed (weights-only GEMM), so
//   V-projection emits Vwo=x*Wvo+bvo directly (transposed), PV' = (E*Vwo)/den
//   writes fp32 h-partials, reduce8 adds sum_h + sum_h(bo). Out-proj GEMM and
//   z2 round-trip eliminated. Softmax fused in S epilogue (exp + row sums).
// Fallback (small ws): proven chunked path.
// ---------------------------------------------------------------------------

typedef __bf16 bf16x8 __attribute__((ext_vector_type(8)));
typedef float  f32x4  __attribute__((ext_vector_type(4)));
typedef short  s16x4  __attribute__((ext_vector_type(4)));

#define AS1 __attribute__((address_space(1)))
#define AS3 __attribute__((address_space(3)))

__device__ inline void gload_lds16(const void* g, void* l) {
  __builtin_amdgcn_global_load_lds((AS1 const void*)g, (AS3 void*)l, 16, 0, 0);
}

__device__ inline unsigned short f2bf(float f) {  // RNE f32 -> bf16 bits
  union { float f; unsigned u; } c; c.f = f;
  unsigned r = c.u + 0x7FFF + ((c.u >> 16) & 1);
  return (unsigned short)(r >> 16);
}
__device__ inline float bf2f(unsigned short u) {
  return __uint_as_float(((unsigned)u) << 16);
}

// XCD-aware bijective remap (T1); valid when total blocks % 8 == 0
__device__ inline void swizzle_bid(int& bx, int& by, int& bz) {
  const int gx = gridDim.x, gy = gridDim.y, gz = gridDim.z;
  const int n = gx * gy * gz;
  if ((n & 7) == 0) {
    int lin = (blockIdx.z * gy + blockIdx.y) * gx + blockIdx.x;
    lin = (lin & 7) * (n >> 3) + (lin >> 3);
    bz = lin / (gx * gy);
    const int rem = lin - bz * gx * gy;
    by = rem / gx;
    bx = rem - by * gx;
  } else {
    bx = blockIdx.x; by = blockIdx.y; bz = blockIdx.z;
  }
}

// ---------------------------------------------------------------------------
// GEMM: C = scale * A * Bt^T (+ bias[z*biasZ + n]); A:[M,lda] bf16, Bt:[N,ldb]
//   zoff  = (z>>zShift)*cZhi + (z & ((1<<zShift)-1))*cZlo
//   rowoff= (m>>rowShift)*cRowHi + (m & ((1<<rowShift)-1))*ldc
// Epilogue modes:
//  - ctOut && z>=ctZmin : C^T bf16 write at
//        ctOut[(z&7)*ctZ + (m0>>10)*ctRowHi + (m0&1023) + n*ctLdc]  (+bias(n))
//  - rowsumOut : e=exp(v*scale) bf16 + row partial sums
//        rowsumOut[(z*8+ntile)*1024+m]                   (fused softmax)
//  - rowScale  : v *= rowScale[z*1024 + (m&1023)] before store (PV normalize)
// T2 swizzle: LDS[row][u16B] holds global[row][u ^ (row&7)]; 0 conflicts.
// Grid: (N/128, M/128, Z). 256 threads = 4 waves, each wave 64x64 output.
// ---------------------------------------------------------------------------
template<bool OUT_F32>
__global__ __launch_bounds__(256, 2)
void gemm_bt_kernel(const unsigned short* __restrict__ A,
                    const unsigned short* __restrict__ Bt,
                    void* __restrict__ Cout,
                    const float* __restrict__ bias,
                    int K, int lda, int ldb,
                    long long aZ, long long bZ,
                    long long cZhi, long long cZlo, int zShift,
                    long long cRowHi, int rowShift, int ldc,
                    long long biasZ, float scale,
                    unsigned short* __restrict__ ctOut, int ctZmin,
                    long long ctZ, long long ctRowHi, int ctLdc,
                    float* __restrict__ rowsumOut,
                    const float* __restrict__ rowScale)
{
  __shared__ unsigned short As[128 * 64];
  __shared__ unsigned short Bs[128 * 64];

  int ntile, mtile, z;
  swizzle_bid(ntile, mtile, z);

  const int tid  = threadIdx.x;
  const int wave = tid >> 6;
  const int lane = tid & 63;
  const int wm = wave >> 1, wn = wave & 1;

  const unsigned short* Ab = A  + (size_t)z * aZ + (size_t)mtile * 128 * lda;
  const unsigned short* Bb = Bt + (size_t)z * bZ + (size_t)ntile * 128 * ldb;

  const int rlane = lane >> 3;                    // 0..7 row within 8-row group
  const int su    = ((lane & 7) ^ rlane) * 8;     // pre-swizzled source unit

  const int rsel  = lane & 15;
  const int usel  = lane & 7;
  const int ubase = lane >> 4;
  const int koff0 = ((ubase) ^ usel) * 8;         // kk=0
  const int koff1 = ((4 | ubase) ^ usel) * 8;     // kk=1

  f32x4 acc[4][4] = {};

  const int nkt = K >> 6;
  for (int kt = 0; kt < nkt; ++kt) {
    const int kbase = kt * 64;
    __syncthreads();
#pragma unroll
    for (int i = 0; i < 4; ++i) {
      const int r = wave * 32 + i * 8;            // wave-uniform base row
      gload_lds16(Ab + (size_t)(r + rlane) * lda + kbase + su, &As[r * 64]);
      gload_lds16(Bb + (size_t)(r + rlane) * ldb + kbase + su, &Bs[r * 64]);
    }
    __syncthreads();
#pragma unroll
    for (int kk = 0; kk < 2; ++kk) {
      const int koff = kk ? koff1 : koff0;
      bf16x8 af[4], bfr[4];
#pragma unroll
      for (int f = 0; f < 4; ++f) {
        af[f]  = *(const bf16x8*)&As[(wm * 64 + f * 16 + rsel) * 64 + koff];
        bfr[f] = *(const bf16x8*)&Bs[(wn * 64 + f * 16 + rsel) * 64 + koff];
      }
#pragma unroll
      for (int fm = 0; fm < 4; ++fm)
#pragma unroll
        for (int fn = 0; fn < 4; ++fn)
          acc[fm][fn] = __builtin_amdgcn_mfma_f32_16x16x32_bf16(af[fm], bfr[fn], acc[fm][fn], 0, 0, 0);
    }
  }

  // C/D frag layout: col = lane&15, row = (lane>>4)*4 + j  [m89]
  if (ctOut && z >= ctZmin) {
    // C^T write (Wvo transposed-weights, or Vwo^T for PV's B operand)
    const long long zo = (long long)(z & 7) * ctZ;
#pragma unroll
    for (int fm = 0; fm < 4; ++fm) {
#pragma unroll
      for (int fn = 0; fn < 4; ++fn) {
        const int n  = ntile * 128 + wn * 64 + fn * 16 + (lane & 15);
        const int m0 = mtile * 128 + wm * 64 + fm * 16 + (lane >> 4) * 4;
        const float bb = bias ? bias[(size_t)z * biasZ + n] : 0.f;
        s16x4 w;
#pragma unroll
        for (int j = 0; j < 4; ++j)
          w[j] = (short)f2bf(acc[fm][fn][j] * scale + bb);
        *(s16x4*)&ctOut[zo + (long long)(m0 >> 10) * ctRowHi + (m0 & 1023)
                        + (long long)n * ctLdc] = w;
      }
    }
    return;
  }

  const long long zoff = (long long)(z >> zShift) * cZhi
                       + (long long)(z & ((1 << zShift) - 1)) * cZlo;

  if (rowsumOut) {
    // fused exp + per-row partial sums (softmax numerator + denominator parts)
    __syncthreads();
    float* redsum = (float*)As;            // [128][2] floats, aliases As
#pragma unroll
    for (int fm = 0; fm < 4; ++fm) {
#pragma unroll
      for (int j = 0; j < 4; ++j) {
        const int m = mtile * 128 + wm * 64 + fm * 16 + (lane >> 4) * 4 + j;
        const long long rowoff = (long long)(m >> rowShift) * cRowHi
                               + (long long)(m & ((1 << rowShift) - 1)) * ldc;
        float part = 0.f;
#pragma unroll
        for (int fn = 0; fn < 4; ++fn) {
          const int n = ntile * 128 + wn * 64 + fn * 16 + (lane & 15);
          const float e = __expf(acc[fm][fn][j] * scale);
          part += e;
          ((unsigned short*)Cout)[zoff + rowoff + n] = f2bf(e);
        }
#pragma unroll
        for (int o = 1; o < 16; o <<= 1) part += __shfl_xor(part, o);
        if ((lane & 15) == 0)
          redsum[(wm * 64 + fm * 16 + (lane >> 4) * 4 + j) * 2 + wn] = part;
      }
    }
    __syncthreads();
    if (tid < 128) {
      const int m = mtile * 128 + tid;
      rowsumOut[((long long)z * 8 + ntile) * 1024 + m] =
          redsum[tid * 2 + 0] + redsum[tid * 2 + 1];
    }
    return;
  }

#pragma unroll
  for (int fm = 0; fm < 4; ++fm) {
#pragma unroll
    for (int j = 0; j < 4; ++j) {
      const int m = mtile * 128 + wm * 64 + fm * 16 + (lane >> 4) * 4 + j;
      const long long rowoff = (long long)(m >> rowShift) * cRowHi
                             + (long long)(m & ((1 << rowShift) - 1)) * ldc;
      const float rsc = rowScale ? rowScale[(size_t)z * 1024 + (m & 1023)] : 1.0f;
#pragma unroll
      for (int fn = 0; fn < 4; ++fn) {
        const int n = ntile * 128 + wn * 64 + fn * 16 + (lane & 15);
        float v = acc[fm][fn][j] * scale;
        if (bias) v += bias[(size_t)z * biasZ + n];
        v *= rsc;
        const long long cidx = zoff + rowoff + n;
        if (OUT_F32) ((float*)Cout)[cidx] = v;
        else ((unsigned short*)Cout)[cidx] = f2bf(v);
      }
    }
  }
}

// weight prep: z<8 wq^T -> wqkvT[z]; z 8-15 wk^T -> wqkvT[z];
// z 16-23 wo[z-16]^T -> woTh[z-16] ([E2][D] per head, outLD=768)
__global__ void prep_weights_kernel(const float* __restrict__ wq,
                                    const float* __restrict__ wk,
                                    const float* __restrict__ wo,
                                    unsigned short* __restrict__ wqkvT,
                                    unsigned short* __restrict__ woTh)
{
  __shared__ float tile[32][33];
  const int z = blockIdx.z;
  const float* in;
  unsigned short* outp;
  if (z < 16) {
    const float* base = (z < 8) ? wq : wk;
    in   = base + (size_t)(z & 7) * 589824;
    outp = wqkvT + (size_t)z * 589824;
  } else {
    in   = wo + (size_t)(z - 16) * 589824;
    outp = woTh + (size_t)(z - 16) * 589824;
  }
  const int c0 = blockIdx.x * 32, r0 = blockIdx.y * 32;
  const int tx = threadIdx.x, ty = threadIdx.y;
#pragma unroll
  for (int i = ty; i < 32; i += 8)
    tile[i][tx] = in[(size_t)(r0 + i) * 768 + c0 + tx];
  __syncthreads();
#pragma unroll
  for (int i = ty; i < 32; i += 8)
    outp[(size_t)(c0 + i) * 768 + r0 + tx] = f2bf(tile[tx][i]);
}

// fp32 [Z][R][C] -> bf16 [Z][C][R] (fallback path)
__global__ void transpose_conv_kernel(const float* __restrict__ in,
                                      unsigned short* __restrict__ out,
                                      int R, int C)
{
  __shared__ float tile[32][33];
  const size_t zo = (size_t)blockIdx.z * R * C;
  const int c0 = blockIdx.x * 32, r0 = blockIdx.y * 32;
  const int tx = threadIdx.x, ty = threadIdx.y;
#pragma unroll
  for (int i = ty; i < 32; i += 8)
    tile[i][tx] = in[zo + (size_t)(r0 + i) * C + c0 + tx];
  __syncthreads();
#pragma unroll
  for (int i = ty; i < 32; i += 8)
    out[zo + (size_t)(c0 + i) * R + r0 + tx] = f2bf(tile[tx][i]);
}

// bf16 [Z][R][C] -> bf16 [Z][C][R] (fallback path)
__global__ void transpose_bf16_kernel(const unsigned short* __restrict__ in,
                                      unsigned short* __restrict__ out,
                                      int R, int C)
{
  __shared__ unsigned short tile[32][33];
  const size_t zo = (size_t)blockIdx.z * R * C;
  const int c0 = blockIdx.x * 32, r0 = blockIdx.y * 32;
  const int tx = threadIdx.x, ty = threadIdx.y;
#pragma unroll
  for (int i = ty; i < 32; i += 8)
    tile[i][tx] = in[zo + (size_t)(r0 + i) * C + c0 + tx];
  __syncthreads();
#pragma unroll
  for (int i = ty; i < 32; i += 8)
    out[zo + (size_t)(c0 + i) * R + r0 + tx] = tile[tx][i];
}

__global__ void convert_f32_bf16_kernel(const float* __restrict__ in,
                                        unsigned short* __restrict__ out, int n4)
{
  const int i = blockIdx.x * blockDim.x + threadIdx.x;
  if (i < n4) {
    const float4 f = ((const float4*)in)[i];
    s16x4 o;
    o[0] = (short)f2bf(f.x); o[1] = (short)f2bf(f.y);
    o[2] = (short)f2bf(f.z); o[3] = (short)f2bf(f.w);
    ((s16x4*)out)[i] = o;
  }
}

__global__ void bosum_kernel(const float* __restrict__ bo, float* __restrict__ bos)
{
  const int e = blockIdx.x * blockDim.x + threadIdx.x;
  if (e < 768) {
    float s = 0.f;
#pragma unroll
    for (int h = 0; h < 8; ++h) s += bo[h * 768 + e];
    bos[e] = s;
  }
}

// bvo[h][e2] = sum_d bv[h][d] * wo[h][d][e2]; grid (3,1,8), 256 thr
__global__ void bvo_kernel(const float* __restrict__ bv,
                           const float* __restrict__ wo,
                           float* __restrict__ bvo)
{
  const int h = blockIdx.z;
  const int e2 = blockIdx.x * 256 + threadIdx.x;
  const float* wob = wo + (size_t)h * 589824;
  const float* bvb = bv + (size_t)h * 768;
  float s = 0.f;
  for (int d = 0; d < 768; ++d) s += bvb[d] * wob[(size_t)d * 768 + e2];
  bvo[(size_t)h * 768 + e2] = s;
}

// concat bq,bk,bvo -> bqkv[24][768] (z = proj*8 + h); bvo rows for z>=16
__global__ void bconcat_kernel(const float* __restrict__ bq,
                               const float* __restrict__ bk,
                               const float* __restrict__ bvo,
                               float* __restrict__ bqkv)
{
  const int i = blockIdx.x * blockDim.x + threadIdx.x;
  if (i < 24 * 768) {
    const int z = i / 768, d = i - z * 768;
    const float* src = (z < 8) ? bq : (z < 16) ? bk : bvo;
    bqkv[i] = src[(z & 7) * 768 + d];
  }
}

// invden[z*1024+t] = 1 / sum_{nt<8} rowsum[(z*8+nt)*1024 + t]
__global__ void invden_kernel(const float* __restrict__ rowsum,
                              float* __restrict__ invden)
{
  const int i = blockIdx.x * blockDim.x + threadIdx.x;
  if (i < 32 * 1024) {
    const int z = i >> 10, t = i & 1023;
    const float* p = rowsum + (size_t)z * 8192 + t;
    float s = 0.f;
#pragma unroll
    for (int nt = 0; nt < 8; ++nt) s += p[nt * 1024];
    invden[i] = 1.0f / s;
  }
}

// out[i] = sum_{h<8} partials[h][i] + bos[col]
__global__ void reduce8_kernel(const float* __restrict__ partials,
                               const float* __restrict__ bos,
                               float* __restrict__ out, int n4)
{
  const int i = blockIdx.x * blockDim.x + threadIdx.x;
  if (i < n4) {
    const long long stride4 = 4096LL * 768 / 4;
    float4 s = ((const float4*)partials)[i];
#pragma unroll
    for (int k2 = 1; k2 < 8; ++k2) {
      float4 p = ((const float4*)partials)[i + k2 * stride4];
      s.x += p.x; s.y += p.y; s.z += p.z; s.w += p.w;
    }
    const int col = (i * 4) % 768;
    const float4 b4 = *(const float4*)&bos[col];
    s.x += b4.x; s.y += b4.y; s.z += b4.z; s.w += b4.w;
    ((float4*)out)[i] = s;
  }
}

// in-place row softmax (fallback path only)
__global__ __launch_bounds__(256)
void softmax_kernel(unsigned short* __restrict__ S)
{
  const size_t row = blockIdx.x;
  unsigned short* p = S + row * 1024;
  const int t = threadIdx.x;

  s16x4 raw = *((const s16x4*)p + t);
  float v[4];
#pragma unroll
  for (int j = 0; j < 4; ++j) v[j] = bf2f((unsigned short)raw[j]);

  float mx = fmaxf(fmaxf(v[0], v[1]), fmaxf(v[2], v[3]));
#pragma unroll
  for (int o = 1; o < 64; o <<= 1) mx = fmaxf(mx, __shfl_xor(mx, o));

  __shared__ float red[8];
  if ((t & 63) == 0) red[t >> 6] = mx;
  __syncthreads();
  mx = fmaxf(fmaxf(red[0], red[1]), fmaxf(red[2], red[3]));

  float e[4], s = 0.f;
#pragma unroll
  for (int j = 0; j < 4; ++j) { e[j] = __expf(v[j] - mx); s += e[j]; }
#pragma unroll
  for (int o = 1; o < 64; o <<= 1) s += __shfl_xor(s, o);
  if ((t & 63) == 0) red[4 + (t >> 6)] = s;
  __syncthreads();
  s = red[4] + red[5] + red[6] + red[7];
  const float inv = 1.0f / s;

  s16x4 outv;
#pragma unroll
  for (int j = 0; j < 4; ++j) outv[j] = (short)f2bf(e[j] * inv);
  *((s16x4*)p + t) = outv;
}

// ---------------------------------------------------------------------------
extern "C" void kernel_launch(void* const* d_in, const int* in_sizes, int n_in,
                              void* d_out, int out_size, void* d_ws, size_t ws_size,
                              hipStream_t stream)
{
  (void)in_sizes; (void)n_in; (void)out_size;
  constexpr int Bb = 4, T = 1024, E = 768, D = 768, H = 8;
  constexpr int HD = H * D;
  constexpr long long TD = (long long)T * D;          // 786432
  constexpr long long TT = (long long)T * T;          // 1048576
  constexpr long long DE = (long long)D * E;          // 589824
  constexpr long long BHTD = (long long)Bb * H * T * D;
  constexpr long long HTD = (long long)H * TD;
  constexpr float SCALE = 0.03608439182435161f;       // 1/sqrt(E)

  const float* x  = (const float*)d_in[0];
  const float* wq = (const float*)d_in[1];
  const float* bq = (const float*)d_in[2];
  const float* wk = (const float*)d_in[3];
  const float* bk = (const float*)d_in[4];
  const float* wv = (const float*)d_in[5];
  const float* bv = (const float*)d_in[6];
  const float* wo = (const float*)d_in[7];
  const float* bo = (const float*)d_in[8];
  float* out = (float*)d_out;

  unsigned char* wsb = (unsigned char*)d_ws;
  const dim3 tb32(32, 8);

  // ---- ALL32 tier peak footprint: 245,443,584 B (unchanged) ----
  if (ws_size >= 245443584ULL + 4096ULL) {
    unsigned short* woTh  = (unsigned short*)(wsb + 0);            //  9,437,184 [8][768][768]
    float*          bos   = (float*)(wsb + 9437184);               //      3,072
    float*          bqkv  = (float*)(wsb + 9440256);               //     73,728
    float*          bvo   = (float*)(wsb + 9513984);               //     24,576
    unsigned short* vT    = (unsigned short*)(wsb + 9538560 + 793088); // align: 10,331,648 -> use fixed:
    // NOTE: keep vT at its proven offset for simplicity:
    vT = (unsigned short*)(wsb + 9513984 + 262144);                // 9,776,128 .. +50,331,648
    unsigned short* qkv   = (unsigned short*)(wsb + 59845632 + 262144); // shift q,k by same pad
    // --- Simpler, re-derived fixed layout (all offsets recomputed): ---
    // [0, 9437184)            woTh
    // [9437184, 9440256)      bos
    // [9440256, 9513984)      bqkv
    // [9513984, 9538560)      bvo
    // [9538560, 59870208)     vT (VwoT) 50,331,648
    // [59870208, 160533504)   q,k (2 x 50,331,648) -- part overlays (100,663,296)
    // [160533504, 227642368)  S 67,108,864 (v-slot region; wvb borrows head)
    // [227642368, 228690944)  rowsum 1,048,576
    // [228690944, 228822016)  invden 131,072
    // [217132032...] wqkvT must NOT overlap S... -> place wqkvT at tail:
    // [228822016, 257133568) would exceed tier; instead wqkvT lives where S
    // later overlays (dead by then):
    vT = (unsigned short*)(wsb + 9538560);
    unsigned short* q    = (unsigned short*)(wsb + 59870208);
    unsigned short* k    = q + BHTD;
    float*          part = (float*)q;                      // after S-GEMM
    unsigned short* S    = (unsigned short*)(wsb + 160533504);
    unsigned short* wvb  = (unsigned short*)(wsb + 160533504);  // dead before S
    float*          rowsum = (float*)(wsb + 227642368);
    float*          invden = (float*)(wsb + 228690944);
    unsigned short* xb     = (unsigned short*)(wsb + 228822016); //  6,291,456
    unsigned short* wqkvT  = (unsigned short*)(wsb + 235113472); // 28,311,552? -> 263,425,024 EXCEEDS
    // wqkvT (28.3MB) won't fit after xb within 245.4MB; but S's region
    // [160533504, 227642368) is free until the S-GEMM, and wqkvT is dead by
    // then. Place wvb at S-head and wqkvT right after it inside S region:
    wvb   = (unsigned short*)(wsb + 160533504);                  // 9,437,184
    wqkvT = (unsigned short*)(wsb + 160533504 + 9437184);        // 28,311,552 ends 198,282,240 < 227,642,368 OK
    // xb stays at 228822016, ends 235,113,472 < 245,443,584 OK.
    qkv = q;  (void)qkv;

    // --- prep ---
    convert_f32_bf16_kernel<<<3072, 256, 0, stream>>>(x, xb, Bb * T * E / 4);
    convert_f32_bf16_kernel<<<(int)(H * DE / 4 + 255) / 256, 256, 0, stream>>>(
        wv, wvb, H * DE / 4);
    prep_weights_kernel<<<dim3(24, 24, 24), tb32, 0, stream>>>(
        wq, wk, wo, wqkvT, woTh);
    bosum_kernel<<<3, 256, 0, stream>>>(bo, bos);
    bvo_kernel<<<dim3(3, 1, 8), 256, 0, stream>>>(bv, wo, bvo);
    bconcat_kernel<<<72, 256, 0, stream>>>(bq, bk, bvo, bqkv);

    // --- WvoT[h][e2][e] = (wv[h]*woTh[h]^T)^T into wqkvT slots 16-23 ---
    // A=wvb [E,D] lda=768, Bt=woTh [E2,D] ldb=768, K=768; CT write.
    gemm_bt_kernel<false><<<dim3(6, 6, 8), 256, 0, stream>>>(
        wvb, woTh, nullptr, nullptr, 768, 768, 768,
        DE, DE, 0LL, 0LL, 30, 0LL, 30, 0, 0LL, 1.0f,
        wqkvT + 16 * DE, 0, DE, 0LL, 768, nullptr, nullptr);

    // --- fused QKV: z=proj*8+h; z<16 -> q,k; z>=16 -> VwoT[b][h][e2][t] (CT)
    gemm_bt_kernel<false><<<dim3(6, 32, 24), 256, 0, stream>>>(
        xb, wqkvT, q, bqkv, E, E, E,
        0LL, DE, BHTD, TD, 3, HTD, 10, D, 768LL, 1.0f,
        vT, 16, TD, HTD, 1024, nullptr, nullptr);

    // --- E = exp(scale * q k^T) + row partial sums ---
    gemm_bt_kernel<false><<<dim3(8, 8, 32), 256, 0, stream>>>(
        q, k, S, nullptr, D, D, D,
        TD, TD, TT, 0LL, 0, 0LL, 30, T, 0LL, SCALE,
        nullptr, 0, 0LL, 0LL, 0, rowsum, nullptr);

    // --- invden ---
    invden_kernel<<<128, 256, 0, stream>>>(rowsum, invden);

    // --- PV': part[h][b*1024+t][e2] = (E * Vwo) * invden  (fp32) ---
    // z=b*8+h: zoff = (z&7)*3145728 + (z>>3)*786432; ldb=1024 over VwoT
    gemm_bt_kernel<true><<<dim3(6, 8, 32), 256, 0, stream>>>(
        S, vT, part, nullptr, T, T, T,
        TT, TD, 786432LL, 3145728LL, 3, 0LL, 30, E, 0LL, 1.0f,
        nullptr, 0, 0LL, 0LL, 0, nullptr, invden);

    // --- out = sum_h part + sum_h bo ---
    reduce8_kernel<<<3072, 256, 0, stream>>>(part, bos, out, 4096 * 768 / 4);
    return;
  }

  // ---------------- fallback: proven chunked path ----------------
  const size_t FIXED = 84937728ULL;
  const size_t PERCH = 8388608ULL;
  int CH = 8;
  while (CH > 1 && FIXED + (size_t)CH * PERCH > ws_size) CH >>= 1;

  size_t off = 0;
  auto carve = [&](size_t bytes) -> void* {
    void* p = wsb + off;
    off += (bytes + 255) & ~(size_t)255;
    return p;
  };
  unsigned short* xb  = (unsigned short*)carve((size_t)Bb * T * E * 2);
  unsigned short* wqT = (unsigned short*)carve((size_t)H * D * E * 2);
  unsigned short* wkT = (unsigned short*)carve((size_t)H * D * E * 2);
  unsigned short* wvT = (unsigned short*)carve((size_t)H * D * E * 2);
  float*          bos = (float*)carve(E * 4);
  unsigned short* z2  = (unsigned short*)carve((size_t)Bb * T * HD * 2);
  unsigned short* qc  = (unsigned short*)carve((size_t)CH * T * D * 2);
  unsigned short* kc  = (unsigned short*)carve((size_t)CH * T * D * 2);
  unsigned short* vc  = (unsigned short*)carve((size_t)CH * T * D * 2);
  unsigned short* vTc = (unsigned short*)carve((size_t)CH * D * T * 2);
  unsigned short* Sc  = (unsigned short*)carve((size_t)CH * T * T * 2);
  unsigned short* woT = wqT;

  convert_f32_bf16_kernel<<<3072, 256, 0, stream>>>(x, xb, Bb * T * E / 4);
  transpose_conv_kernel<<<dim3(24, 24, 8), tb32, 0, stream>>>(wq, wqT, E, D);
  transpose_conv_kernel<<<dim3(24, 24, 8), tb32, 0, stream>>>(wk, wkT, E, D);
  transpose_conv_kernel<<<dim3(24, 24, 8), tb32, 0, stream>>>(wv, wvT, E, D);
  bosum_kernel<<<3, 256, 0, stream>>>(bo, bos);

  constexpr long long DT = (long long)D * T;
  const int nchunks = (Bb * H) / CH;
  for (int c = 0; c < nchunks; ++c) {
    const int z0 = c * CH;
    const int b  = z0 >> 3;
    const int h0 = z0 & 7;
    const unsigned short* xbb = xb + (size_t)b * T * E;

    gemm_bt_kernel<false><<<dim3(6, 8, CH), 256, 0, stream>>>(
        xbb, wqT + (size_t)h0 * DE, qc, bq + (size_t)h0 * D, E, E, E,
        0LL, DE, TD, 0LL, 0, 0LL, 30, D, (long long)D, 1.0f,
        nullptr, 0, 0LL, 0LL, 0, nullptr, nullptr);
    gemm_bt_kernel<false><<<dim3(6, 8, CH), 256, 0, stream>>>(
        xbb, wkT + (size_t)h0 * DE, kc, bk + (size_t)h0 * D, E, E, E,
        0LL, DE, TD, 0LL, 0, 0LL, 30, D, (long long)D, 1.0f,
        nullptr, 0, 0LL, 0LL, 0, nullptr, nullptr);
    gemm_bt_kernel<false><<<dim3(6, 8, CH), 256, 0, stream>>>(
        xbb, wvT + (size_t)h0 * DE, vc, bv + (size_t)h0 * D, E, E, E,
        0LL, DE, TD, 0LL, 0, 0LL, 30, D, (long long)D, 1.0f,
        nullptr, 0, 0LL, 0LL, 0, nullptr, nullptr);

    transpose_bf16_kernel<<<dim3(24, 32, CH), tb32, 0, stream>>>(vc, vTc, T, D);

    gemm_bt_kernel<false><<<dim3(8, 8, CH), 256, 0, stream>>>(
        qc, kc, Sc, nullptr, D, D, D,
        TD, TD, TT, 0LL, 0, 0LL, 30, T, 0LL, SCALE,
        nullptr, 0, 0LL, 0LL, 0, nullptr, nullptr);

    softmax_kernel<<<CH * T, 256, 0, stream>>>(Sc);

    gemm_bt_kernel<false><<<dim3(6, 8, CH), 256, 0, stream>>>(
        Sc, vTc, z2 + (size_t)b * T * HD + (size_t)h0 * D, nullptr, T, T, T,
        TT, DT, (long long)D, 0LL, 0, 0LL, 30, HD, 0LL, 1.0f,
        nullptr, 0, 0LL, 0LL, 0, nullptr, nullptr);
  }

  transpose_conv_kernel<<<dim3(24, 192, 1), tb32, 0, stream>>>(wo, woT, HD, E);
  gemm_bt_kernel<true><<<dim3(6, 32, 1), 256, 0, stream>>>(
      z2, woT, out, bos, HD, HD, HD,
      0LL, 0LL, 0LL, 0LL, 0, 0LL, 30, E, 0LL, 1.0f,
      nullptr, 0, 0LL, 0LL, 0, nullptr, nullptr);
}

// Round 11
// 355.826 us; speedup vs baseline: 1.0991x; 1.0991x over previous
//
#include <hip/hip_runtime.h>
#include <hip/hip_bf16.h>

// ---------------------------------------------------------------------------
// MultiHeadAttention: B=4, T=1024, E=768, D=768, H=8, per-head full-width proj
// REVERT to measured-best (356.3us, R7 bench): 128x128-tile 4-wave bf16 MFMA
// GEMM + T2 LDS XOR swizzle (0 conflicts) + T1 XCD swizzle, launch_bounds(256,2).
// Fusions: QKV epilogue writes V^T directly; S epilogue = exp + row partial
// sums (softmax denom factored into PV epilogue via invden); out-proj
// split-K=4 + reduce4; merged 32-slice weight prep.
// Subsequent experiments all <=0: launch_bounds(256,4) null (R9), Wvo-fold
// regression (R10), three 256^2 schedule nulls (R4/R5/R8).
// Fallback (small ws): proven chunked path.
// ---------------------------------------------------------------------------

typedef __bf16 bf16x8 __attribute__((ext_vector_type(8)));
typedef float  f32x4  __attribute__((ext_vector_type(4)));
typedef short  s16x4  __attribute__((ext_vector_type(4)));

#define AS1 __attribute__((address_space(1)))
#define AS3 __attribute__((address_space(3)))

__device__ inline void gload_lds16(const void* g, void* l) {
  // async global->LDS, 16B/lane; LDS dest wave-uniform base + lane*16
  __builtin_amdgcn_global_load_lds((AS1 const void*)g, (AS3 void*)l, 16, 0, 0);
}

__device__ inline unsigned short f2bf(float f) {  // RNE f32 -> bf16 bits
  union { float f; unsigned u; } c; c.f = f;
  unsigned r = c.u + 0x7FFF + ((c.u >> 16) & 1);
  return (unsigned short)(r >> 16);
}
__device__ inline float bf2f(unsigned short u) {
  return __uint_as_float(((unsigned)u) << 16);
}

// XCD-aware bijective remap (T1); valid when total blocks % 8 == 0
__device__ inline void swizzle_bid(int& bx, int& by, int& bz) {
  const int gx = gridDim.x, gy = gridDim.y, gz = gridDim.z;
  const int n = gx * gy * gz;
  if ((n & 7) == 0) {
    int lin = (blockIdx.z * gy + blockIdx.y) * gx + blockIdx.x;
    lin = (lin & 7) * (n >> 3) + (lin >> 3);
    bz = lin / (gx * gy);
    const int rem = lin - bz * gx * gy;
    by = rem / gx;
    bx = rem - by * gx;
  } else {
    bx = blockIdx.x; by = blockIdx.y; bz = blockIdx.z;
  }
}

// ---------------------------------------------------------------------------
// GEMM: C = scale * A * Bt^T (+ bias[z*biasZ + n]); A:[M,lda] bf16, Bt:[N,ldb]
//   zoff  = (z>>zShift)*cZhi + (z & ((1<<zShift)-1))*cZlo
//   rowoff= (m>>rowShift)*cRowHi + (m & ((1<<rowShift)-1))*ldc
//   C[zoff + rowoff + n]
// T2 swizzle: LDS[row][u16B] holds global[row][u ^ (row&7)] (pre-swizzled
// source, linear gload_lds dest); reads XOR the unit back. 0 conflicts (R4-R10).
// Epilogue modes:
//  - vtOut && z>=16  : write C^T into vtOut[b][z-16][n][t] (fused V^T)
//  - rowsumOut       : e=exp(v*scale); write e (bf16) + per-row partial sums
//                      rowsumOut[(z*8+ntile)*1024 + m]   (softmax fused)
//  - rowScale        : v *= rowScale[z*1024+m] before store (PV normalization)
// Grid: (N/128, M/128, Z). 256 threads = 4 waves, each wave 64x64 output.
// ---------------------------------------------------------------------------
template<bool OUT_F32>
__global__ __launch_bounds__(256, 2)
void gemm_bt_kernel(const unsigned short* __restrict__ A,
                    const unsigned short* __restrict__ Bt,
                    void* __restrict__ Cout,
                    const float* __restrict__ bias,
                    int K, int lda, int ldb,
                    long long aZ, long long bZ,
                    long long cZhi, long long cZlo, int zShift,
                    long long cRowHi, int rowShift, int ldc,
                    long long biasZ, float scale,
                    unsigned short* __restrict__ vtOut,
                    float* __restrict__ rowsumOut,
                    const float* __restrict__ rowScale)
{
  __shared__ unsigned short As[128 * 64];
  __shared__ unsigned short Bs[128 * 64];

  int ntile, mtile, z;
  swizzle_bid(ntile, mtile, z);

  const int tid  = threadIdx.x;
  const int wave = tid >> 6;
  const int lane = tid & 63;
  const int wm = wave >> 1, wn = wave & 1;

  const unsigned short* Ab = A  + (size_t)z * aZ + (size_t)mtile * 128 * lda;
  const unsigned short* Bb = Bt + (size_t)z * bZ + (size_t)ntile * 128 * ldb;

  const int rlane = lane >> 3;                    // 0..7 row within 8-row group
  const int su    = ((lane & 7) ^ rlane) * 8;     // pre-swizzled source unit

  // swizzled frag-read offsets: u_log = kk*4 + (lane>>4); u_phys = u_log^(lane&7)
  const int rsel  = lane & 15;
  const int usel  = lane & 7;
  const int ubase = lane >> 4;
  const int koff0 = ((ubase) ^ usel) * 8;         // kk=0
  const int koff1 = ((4 | ubase) ^ usel) * 8;     // kk=1

  f32x4 acc[4][4] = {};

  const int nkt = K >> 6;
  for (int kt = 0; kt < nkt; ++kt) {
    const int kbase = kt * 64;
    __syncthreads();
#pragma unroll
    for (int i = 0; i < 4; ++i) {
      const int r = wave * 32 + i * 8;            // wave-uniform base row
      gload_lds16(Ab + (size_t)(r + rlane) * lda + kbase + su, &As[r * 64]);
      gload_lds16(Bb + (size_t)(r + rlane) * ldb + kbase + su, &Bs[r * 64]);
    }
    __syncthreads();
#pragma unroll
    for (int kk = 0; kk < 2; ++kk) {
      const int koff = kk ? koff1 : koff0;
      bf16x8 af[4], bfr[4];
#pragma unroll
      for (int f = 0; f < 4; ++f) {
        af[f]  = *(const bf16x8*)&As[(wm * 64 + f * 16 + rsel) * 64 + koff];
        bfr[f] = *(const bf16x8*)&Bs[(wn * 64 + f * 16 + rsel) * 64 + koff];
      }
#pragma unroll
      for (int fm = 0; fm < 4; ++fm)
#pragma unroll
        for (int fn = 0; fn < 4; ++fn)
          acc[fm][fn] = __builtin_amdgcn_mfma_f32_16x16x32_bf16(af[fm], bfr[fn], acc[fm][fn], 0, 0, 0);
    }
  }

  // C/D frag layout: col = lane&15, row = (lane>>4)*4 + j  [m89]
  if (vtOut && z >= 16) {
    // fused V^T: vT[b][h][d][t], h = z-16; m = b*1024 + t, n = d
    const long long hoff = (long long)(z - 16) * 786432LL;   // D*T
#pragma unroll
    for (int fm = 0; fm < 4; ++fm) {
#pragma unroll
      for (int fn = 0; fn < 4; ++fn) {
        const int n  = ntile * 128 + wn * 64 + fn * 16 + (lane & 15);
        const int m0 = mtile * 128 + wm * 64 + fm * 16 + (lane >> 4) * 4;
        const int b  = m0 >> 10, t0 = m0 & 1023;
        const float bb = bias ? bias[(size_t)z * biasZ + n] : 0.f;
        s16x4 w;
#pragma unroll
        for (int j = 0; j < 4; ++j)
          w[j] = (short)f2bf(acc[fm][fn][j] * scale + bb);
        *(s16x4*)&vtOut[(size_t)b * 6291456 + hoff + (size_t)n * 1024 + t0] = w;
      }
    }
    return;
  }

  const long long zoff = (long long)(z >> zShift) * cZhi
                       + (long long)(z & ((1 << zShift) - 1)) * cZlo;

  if (rowsumOut) {
    // fused exp + per-row partial sums (softmax numerator + denominator parts)
    __syncthreads();                       // all waves done reading As/Bs
    float* redsum = (float*)As;            // [128][2] floats, aliases As
#pragma unroll
    for (int fm = 0; fm < 4; ++fm) {
#pragma unroll
      for (int j = 0; j < 4; ++j) {
        const int m = mtile * 128 + wm * 64 + fm * 16 + (lane >> 4) * 4 + j;
        const long long rowoff = (long long)(m >> rowShift) * cRowHi
                               + (long long)(m & ((1 << rowShift) - 1)) * ldc;
        float part = 0.f;
#pragma unroll
        for (int fn = 0; fn < 4; ++fn) {
          const int n = ntile * 128 + wn * 64 + fn * 16 + (lane & 15);
          const float e = __expf(acc[fm][fn][j] * scale);
          part += e;
          ((unsigned short*)Cout)[zoff + rowoff + n] = f2bf(e);
        }
#pragma unroll
        for (int o = 1; o < 16; o <<= 1) part += __shfl_xor(part, o);
        if ((lane & 15) == 0)
          redsum[(wm * 64 + fm * 16 + (lane >> 4) * 4 + j) * 2 + wn] = part;
      }
    }
    __syncthreads();
    if (tid < 128) {
      const int m = mtile * 128 + tid;
      rowsumOut[((long long)z * 8 + ntile) * 1024 + m] =
          redsum[tid * 2 + 0] + redsum[tid * 2 + 1];
    }
    return;
  }

#pragma unroll
  for (int fm = 0; fm < 4; ++fm) {
#pragma unroll
    for (int j = 0; j < 4; ++j) {
      const int m = mtile * 128 + wm * 64 + fm * 16 + (lane >> 4) * 4 + j;
      const long long rowoff = (long long)(m >> rowShift) * cRowHi
                             + (long long)(m & ((1 << rowShift) - 1)) * ldc;
      const float rsc = rowScale ? rowScale[(size_t)z * 1024 + (m & 1023)] : 1.0f;
#pragma unroll
      for (int fn = 0; fn < 4; ++fn) {
        const int n = ntile * 128 + wn * 64 + fn * 16 + (lane & 15);
        float v = acc[fm][fn][j] * scale;
        if (bias) v += bias[(size_t)z * biasZ + n];
        v *= rsc;
        const long long cidx = zoff + rowoff + n;
        if (OUT_F32) ((float*)Cout)[cidx] = v;
        else ((unsigned short*)Cout)[cidx] = f2bf(v);
      }
    }
  }
}

// merged weight prep: z<24 -> wq/wk/wv head (z&7) -> wqkvT[z]; z>=24 -> woT
__global__ void prep_weights_kernel(const float* __restrict__ wq,
                                    const float* __restrict__ wk,
                                    const float* __restrict__ wv,
                                    const float* __restrict__ wo,
                                    unsigned short* __restrict__ wqkvT,
                                    unsigned short* __restrict__ woT)
{
  __shared__ float tile[32][33];
  const int z = blockIdx.z;
  const float* in;
  unsigned short* outp;
  int outLD;
  if (z < 24) {
    const float* base = (z < 8) ? wq : (z < 16) ? wk : wv;
    in   = base + (size_t)(z & 7) * 589824;
    outp = wqkvT + (size_t)z * 589824;
    outLD = 768;
  } else {
    in   = wo + (size_t)(z - 24) * 589824;
    outp = woT + (size_t)(z - 24) * 768;
    outLD = 6144;
  }
  const int c0 = blockIdx.x * 32, r0 = blockIdx.y * 32;
  const int tx = threadIdx.x, ty = threadIdx.y;
#pragma unroll
  for (int i = ty; i < 32; i += 8)
    tile[i][tx] = in[(size_t)(r0 + i) * 768 + c0 + tx];
  __syncthreads();
#pragma unroll
  for (int i = ty; i < 32; i += 8)
    outp[(size_t)(c0 + i) * outLD + r0 + tx] = f2bf(tile[tx][i]);
}

// fp32 [Z][R][C] -> bf16 [Z][C][R] (fallback path)
__global__ void transpose_conv_kernel(const float* __restrict__ in,
                                      unsigned short* __restrict__ out,
                                      int R, int C)
{
  __shared__ float tile[32][33];
  const size_t zo = (size_t)blockIdx.z * R * C;
  const int c0 = blockIdx.x * 32, r0 = blockIdx.y * 32;
  const int tx = threadIdx.x, ty = threadIdx.y;
#pragma unroll
  for (int i = ty; i < 32; i += 8)
    tile[i][tx] = in[zo + (size_t)(r0 + i) * C + c0 + tx];
  __syncthreads();
#pragma unroll
  for (int i = ty; i < 32; i += 8)
    out[zo + (size_t)(c0 + i) * R + r0 + tx] = f2bf(tile[tx][i]);
}

// bf16 [Z][R][C] -> bf16 [Z][C][R] (fallback path)
__global__ void transpose_bf16_kernel(const unsigned short* __restrict__ in,
                                      unsigned short* __restrict__ out,
                                      int R, int C)
{
  __shared__ unsigned short tile[32][33];
  const size_t zo = (size_t)blockIdx.z * R * C;
  const int c0 = blockIdx.x * 32, r0 = blockIdx.y * 32;
  const int tx = threadIdx.x, ty = threadIdx.y;
#pragma unroll
  for (int i = ty; i < 32; i += 8)
    tile[i][tx] = in[zo + (size_t)(r0 + i) * C + c0 + tx];
  __syncthreads();
#pragma unroll
  for (int i = ty; i < 32; i += 8)
    out[zo + (size_t)(c0 + i) * R + r0 + tx] = tile[tx][i];
}

__global__ void convert_f32_bf16_kernel(const float* __restrict__ in,
                                        unsigned short* __restrict__ out, int n4)
{
  const int i = blockIdx.x * blockDim.x + threadIdx.x;
  if (i < n4) {
    const float4 f = ((const float4*)in)[i];
    s16x4 o;
    o[0] = (short)f2bf(f.x); o[1] = (short)f2bf(f.y);
    o[2] = (short)f2bf(f.z); o[3] = (short)f2bf(f.w);
    ((s16x4*)out)[i] = o;
  }
}

__global__ void bosum_kernel(const float* __restrict__ bo, float* __restrict__ bos)
{
  const int e = blockIdx.x * blockDim.x + threadIdx.x;
  if (e < 768) {
    float s = 0.f;
#pragma unroll
    for (int h = 0; h < 8; ++h) s += bo[h * 768 + e];
    bos[e] = s;
  }
}

__global__ void bconcat_kernel(const float* __restrict__ bq,
                               const float* __restrict__ bk,
                               const float* __restrict__ bv,
                               float* __restrict__ bqkv)
{
  const int i = blockIdx.x * blockDim.x + threadIdx.x;
  if (i < 24 * 768) {
    const int z = i / 768, d = i - z * 768;
    const float* src = (z < 8) ? bq : (z < 16) ? bk : bv;
    bqkv[i] = src[(z & 7) * 768 + d];
  }
}

// invden[z*1024+t] = 1 / sum_{nt<8} rowsum[(z*8+nt)*1024 + t]
__global__ void invden_kernel(const float* __restrict__ rowsum,
                              float* __restrict__ invden)
{
  const int i = blockIdx.x * blockDim.x + threadIdx.x;
  if (i < 32 * 1024) {
    const int z = i >> 10, t = i & 1023;
    const float* p = rowsum + (size_t)z * 8192 + t;
    float s = 0.f;
#pragma unroll
    for (int nt = 0; nt < 8; ++nt) s += p[nt * 1024];
    invden[i] = 1.0f / s;
  }
}

__global__ void reduce4_kernel(const float* __restrict__ partials,
                               const float* __restrict__ bos,
                               float* __restrict__ out, int n4)
{
  const int i = blockIdx.x * blockDim.x + threadIdx.x;
  if (i < n4) {
    const long long stride4 = 4096LL * 768 / 4;
    float4 a = ((const float4*)partials)[i];
    float4 b = ((const float4*)partials)[i + stride4];
    float4 c = ((const float4*)partials)[i + 2 * stride4];
    float4 d = ((const float4*)partials)[i + 3 * stride4];
    const int col = (i * 4) % 768;
    const float4 b4 = *(const float4*)&bos[col];
    float4 r;
    r.x = a.x + b.x + c.x + d.x + b4.x;
    r.y = a.y + b.y + c.y + d.y + b4.y;
    r.z = a.z + b.z + c.z + d.z + b4.z;
    r.w = a.w + b.w + c.w + d.w + b4.w;
    ((float4*)out)[i] = r;
  }
}

// in-place row softmax (fallback path only)
__global__ __launch_bounds__(256)
void softmax_kernel(unsigned short* __restrict__ S)
{
  const size_t row = blockIdx.x;
  unsigned short* p = S + row * 1024;
  const int t = threadIdx.x;

  s16x4 raw = *((const s16x4*)p + t);
  float v[4];
#pragma unroll
  for (int j = 0; j < 4; ++j) v[j] = bf2f((unsigned short)raw[j]);

  float mx = fmaxf(fmaxf(v[0], v[1]), fmaxf(v[2], v[3]));
#pragma unroll
  for (int o = 1; o < 64; o <<= 1) mx = fmaxf(mx, __shfl_xor(mx, o));

  __shared__ float red[8];
  if ((t & 63) == 0) red[t >> 6] = mx;
  __syncthreads();
  mx = fmaxf(fmaxf(red[0], red[1]), fmaxf(red[2], red[3]));

  float e[4], s = 0.f;
#pragma unroll
  for (int j = 0; j < 4; ++j) { e[j] = __expf(v[j] - mx); s += e[j]; }
#pragma unroll
  for (int o = 1; o < 64; o <<= 1) s += __shfl_xor(s, o);
  if ((t & 63) == 0) red[4 + (t >> 6)] = s;
  __syncthreads();
  s = red[4] + red[5] + red[6] + red[7];
  const float inv = 1.0f / s;

  s16x4 outv;
#pragma unroll
  for (int j = 0; j < 4; ++j) outv[j] = (short)f2bf(e[j] * inv);
  *((s16x4*)p + t) = outv;
}

// ---------------------------------------------------------------------------
extern "C" void kernel_launch(void* const* d_in, const int* in_sizes, int n_in,
                              void* d_out, int out_size, void* d_ws, size_t ws_size,
                              hipStream_t stream)
{
  (void)in_sizes; (void)n_in; (void)out_size;
  constexpr int Bb = 4, T = 1024, E = 768, D = 768, H = 8;
  constexpr int HD = H * D;
  constexpr long long TD = (long long)T * D;
  constexpr long long TT = (long long)T * T;
  constexpr long long DE = (long long)D * E;
  constexpr long long DT = (long long)D * T;
  constexpr long long BHTD = (long long)Bb * H * T * D;
  constexpr long long HTD = (long long)H * TD;
  constexpr float SCALE = 0.03608439182435161f;   // 1/sqrt(E)

  const float* x  = (const float*)d_in[0];
  const float* wq = (const float*)d_in[1];
  const float* bq = (const float*)d_in[2];
  const float* wk = (const float*)d_in[3];
  const float* bk = (const float*)d_in[4];
  const float* wv = (const float*)d_in[5];
  const float* bv = (const float*)d_in[6];
  const float* wo = (const float*)d_in[7];
  const float* bo = (const float*)d_in[8];
  float* out = (float*)d_out;

  unsigned char* wsb = (unsigned char*)d_ws;
  const dim3 tb32(32, 8);

  // ---- ALL32 tier peak footprint: 245,443,584 B ----
  if (ws_size >= 245443584ULL + 4096ULL) {
    unsigned short* woT   = (unsigned short*)(wsb + 0);
    float*          bos   = (float*)(wsb + 9437184);
    float*          bqkv  = (float*)(wsb + 9440256);
    unsigned short* vT    = (unsigned short*)(wsb + 9513984);
    unsigned short* qkv   = (unsigned short*)(wsb + 59845632);
    unsigned short* q     = qkv;
    unsigned short* k     = qkv + BHTD;
    unsigned short* xb    = (unsigned short*)(wsb + 210840576);
    unsigned short* wqkvT = (unsigned short*)(wsb + 217132032);
    unsigned short* S     = qkv + 2 * BHTD;   // v region; overlays xb+wqkvT head
    float*          part  = (float*)k;        // 4x12.6MB fits dead k exactly
    unsigned short* z2    = q;                // overlays dead q
    float*          rowsum = (float*)(wsb + 227617792);
    float*          invden = (float*)(wsb + 228666368);

    // --- prep ---
    convert_f32_bf16_kernel<<<3072, 256, 0, stream>>>(x, xb, Bb * T * E / 4);
    prep_weights_kernel<<<dim3(24, 24, 32), tb32, 0, stream>>>(
        wq, wk, wv, wo, wqkvT, woT);
    bosum_kernel<<<3, 256, 0, stream>>>(bo, bos);
    bconcat_kernel<<<72, 256, 0, stream>>>(bq, bk, bv, bqkv);

    // --- fused QKV: z = proj*8 + h; z>=16 (V) writes vT[b][h][d][t] directly
    gemm_bt_kernel<false><<<dim3(6, 32, 24), 256, 0, stream>>>(
        xb, wqkvT, qkv, bqkv, E, E, E,
        0LL, DE, BHTD, TD, 3, HTD, 10, D, 768LL, 1.0f, vT, nullptr, nullptr);

    // --- E = exp(scale * q k^T) + row partial sums (fused softmax part 1) ---
    gemm_bt_kernel<false><<<dim3(8, 8, 32), 256, 0, stream>>>(
        q, k, S, nullptr, D, D, D,
        TD, TD, TT, 0LL, 0, 0LL, 30, T, 0LL, SCALE, nullptr, rowsum, nullptr);

    // --- invden[z][t] = 1/sum (fused softmax part 2) ---
    invden_kernel<<<128, 256, 0, stream>>>(rowsum, invden);

    // --- z2[b,t,h*D+n] = (E v) * invden : z = b*8+h ---
    gemm_bt_kernel<false><<<dim3(6, 8, 32), 256, 0, stream>>>(
        S, vT, z2, nullptr, T, T, T,
        TT, DT, (long long)T * HD, (long long)D, 3, 0LL, 30, HD, 0LL, 1.0f,
        nullptr, nullptr, invden);

    // --- out-proj split-K=4: partials[kz][4096][768] fp32 ---
    gemm_bt_kernel<true><<<dim3(6, 32, 4), 256, 0, stream>>>(
        z2, woT, part, nullptr, 1536, HD, HD,
        1536LL, 1536LL, 3145728LL, 0LL, 0, 0LL, 30, E, 0LL, 1.0f,
        nullptr, nullptr, nullptr);
    reduce4_kernel<<<3072, 256, 0, stream>>>(part, bos, out, 4096 * 768 / 4);
    return;
  }

  // ---------------- fallback: proven chunked path ----------------
  const size_t FIXED = 84937728ULL;
  const size_t PERCH = 8388608ULL;
  int CH = 8;
  while (CH > 1 && FIXED + (size_t)CH * PERCH > ws_size) CH >>= 1;

  size_t off = 0;
  auto carve = [&](size_t bytes) -> void* {
    void* p = wsb + off;
    off += (bytes + 255) & ~(size_t)255;
    return p;
  };
  unsigned short* xb  = (unsigned short*)carve((size_t)Bb * T * E * 2);
  unsigned short* wqT = (unsigned short*)carve((size_t)H * D * E * 2);
  unsigned short* wkT = (unsigned short*)carve((size_t)H * D * E * 2);
  unsigned short* wvT = (unsigned short*)carve((size_t)H * D * E * 2);
  float*          bos = (float*)carve(E * 4);
  unsigned short* z2  = (unsigned short*)carve((size_t)Bb * T * HD * 2);
  unsigned short* qc  = (unsigned short*)carve((size_t)CH * T * D * 2);
  unsigned short* kc  = (unsigned short*)carve((size_t)CH * T * D * 2);
  unsigned short* vc  = (unsigned short*)carve((size_t)CH * T * D * 2);
  unsigned short* vTc = (unsigned short*)carve((size_t)CH * D * T * 2);
  unsigned short* Sc  = (unsigned short*)carve((size_t)CH * T * T * 2);
  unsigned short* woT = wqT;

  convert_f32_bf16_kernel<<<3072, 256, 0, stream>>>(x, xb, Bb * T * E / 4);
  transpose_conv_kernel<<<dim3(24, 24, 8), tb32, 0, stream>>>(wq, wqT, E, D);
  transpose_conv_kernel<<<dim3(24, 24, 8), tb32, 0, stream>>>(wk, wkT, E, D);
  transpose_conv_kernel<<<dim3(24, 24, 8), tb32, 0, stream>>>(wv, wvT, E, D);
  bosum_kernel<<<3, 256, 0, stream>>>(bo, bos);

  const int nchunks = (Bb * H) / CH;
  for (int c = 0; c < nchunks; ++c) {
    const int z0 = c * CH;
    const int b  = z0 >> 3;
    const int h0 = z0 & 7;
    const unsigned short* xbb = xb + (size_t)b * T * E;

    gemm_bt_kernel<false><<<dim3(6, 8, CH), 256, 0, stream>>>(
        xbb, wqT + (size_t)h0 * DE, qc, bq + (size_t)h0 * D, E, E, E,
        0LL, DE, TD, 0LL, 0, 0LL, 30, D, (long long)D, 1.0f,
        nullptr, nullptr, nullptr);
    gemm_bt_kernel<false><<<dim3(6, 8, CH), 256, 0, stream>>>(
        xbb, wkT + (size_t)h0 * DE, kc, bk + (size_t)h0 * D, E, E, E,
        0LL, DE, TD, 0LL, 0, 0LL, 30, D, (long long)D, 1.0f,
        nullptr, nullptr, nullptr);
    gemm_bt_kernel<false><<<dim3(6, 8, CH), 256, 0, stream>>>(
        xbb, wvT + (size_t)h0 * DE, vc, bv + (size_t)h0 * D, E, E, E,
        0LL, DE, TD, 0LL, 0, 0LL, 30, D, (long long)D, 1.0f,
        nullptr, nullptr, nullptr);

    transpose_bf16_kernel<<<dim3(24, 32, CH), tb32, 0, stream>>>(vc, vTc, T, D);

    gemm_bt_kernel<false><<<dim3(8, 8, CH), 256, 0, stream>>>(
        qc, kc, Sc, nullptr, D, D, D,
        TD, TD, TT, 0LL, 0, 0LL, 30, T, 0LL, SCALE,
        nullptr, nullptr, nullptr);

    softmax_kernel<<<CH * T, 256, 0, stream>>>(Sc);

    gemm_bt_kernel<false><<<dim3(6, 8, CH), 256, 0, stream>>>(
        Sc, vTc, z2 + (size_t)b * T * HD + (size_t)h0 * D, nullptr, T, T, T,
        TT, DT, (long long)D, 0LL, 0, 0LL, 30, HD, 0LL, 1.0f,
        nullptr, nullptr, nullptr);
  }

  transpose_conv_kernel<<<dim3(24, 192, 1), tb32, 0, stream>>>(wo, woT, HD, E);
  gemm_bt_kernel<true><<<dim3(6, 32, 1), 256, 0, stream>>>(
      z2, woT, out, bos, HD, HD, HD,
      0LL, 0LL, 0LL, 0LL, 0, 0LL, 30, E, 0LL, 1.0f,
      nullptr, nullptr, nullptr);
}